// Round 5
// baseline (127.096 us; speedup 1.0000x reference)
//
#include <hip/hip_runtime.h>
#include <hip/hip_bf16.h>
#include <hip/hip_cooperative_groups.h>

namespace cg = cooperative_groups;

// Problem: B=8, CIN=8, COUT=8, NX=NT=512, M1=M2=4.
// out[b,o,z,i] = Re( sum_{m,kw} c2[b,o,m,kw] e^{2pi i (m z + kw i)/512} ) / 65536
// partial2 layout: [b][kw][ci][y] float2

#define PI2 6.283185307179586f

// fold-reduce: after this, lanes with (lane&msk)==0 hold u summed over that
// lane bit; lanes with (lane&msk)!=0 hold v summed over that bit.
__device__ __forceinline__ float foldred(float u, float v, int msk, int lane) {
    float send = (lane & msk) ? u : v;
    float recv = __shfl_xor(send, msk, 64);
    return ((lane & msk) ? v : u) + recv;
}

// ---- Phase 1 body: t-DFT (4 modes) for row task=(bc,y). bs/bc_ = sincos of lane angle.
__device__ __forceinline__ void dft_t_row(const float* __restrict__ x, float* __restrict__ pf,
                                          int task, int lane, float bs, float bc_) {
    int bc = task >> 8;           // b*8+cin
    int y  = task & 255;
    const float2* row2 = (const float2*)(x + ((size_t)bc * 512 + (size_t)(2 * y)) * 512);
    float v[4];
#pragma unroll
    for (int k = 0; k < 4; ++k) v[k] = row2[lane + 64 * k].x;   // x[..,2t], t=lane+64k

    float pr[4], pim[4];
    pr[0] = 1.f;                         pim[0] = 0.f;
    pr[1] = bc_;                         pim[1] = -bs;
    pr[2] = pr[1]*pr[1] - pim[1]*pim[1]; pim[2] = 2.f*pr[1]*pim[1];
    pr[3] = pr[2]*pr[1] - pim[2]*pim[1]; pim[3] = pr[2]*pim[1] + pim[2]*pr[1];

    float ar[4] = {0.f,0.f,0.f,0.f};
    float ai[4] = {0.f,0.f,0.f,0.f};
#pragma unroll
    for (int k = 0; k < 4; ++k) {
#pragma unroll
        for (int kw = 0; kw < 4; ++kw) {
            int n = (k * kw) & 3;          // twiddle = p[kw] * (-i)^n
            float rr, ri;
            if      (n == 0) { rr =  pr[kw];  ri =  pim[kw]; }
            else if (n == 1) { rr =  pim[kw]; ri = -pr[kw];  }
            else if (n == 2) { rr = -pr[kw];  ri = -pim[kw]; }
            else             { rr = -pim[kw]; ri =  pr[kw];  }
            ar[kw] += v[k] * rr;
            ai[kw] += v[k] * ri;
        }
    }
    float A0 = foldred(ar[0], ai[0], 1, lane);
    float A1 = foldred(ar[1], ai[1], 1, lane);
    float A2 = foldred(ar[2], ai[2], 1, lane);
    float A3 = foldred(ar[3], ai[3], 1, lane);
    float B0 = foldred(A0, A1, 2, lane);
    float B1 = foldred(A2, A3, 2, lane);
    float C  = foldred(B0, B1, 4, lane);
    C += __shfl_xor(C, 8, 64);
    C += __shfl_xor(C, 16, 64);
    C += __shfl_xor(C, 32, 64);
    if (lane < 8) {
        int kw = lane >> 1, ri = lane & 1;
        int b = bc >> 3, ci = bc & 7;
        pf[(((size_t)(b * 4 + kw) * 8 + ci) * 256 + y) * 2 + ri] = C;
    }
}

// ---- Phase 2 body: fused y-DFT + channel mix for task=(b,kw,midx,o).
__device__ __forceinline__ void mix_y_task(const float2* __restrict__ partial2,
                                           const float* __restrict__ w1,
                                           const float* __restrict__ w2,
                                           float* __restrict__ c2f, int task, int lane) {
    int o = task & 7, midx = (task >> 3) & 7, kw = (task >> 6) & 3, b = task >> 8;
    float m = (midx < 4) ? (float)midx : (float)(midx - 8);
    const float* w = (midx < 4) ? w1 : w2;
    int mx = midx & 3;

    float wr[8], wi[8];
#pragma unroll
    for (int ci = 0; ci < 8; ++ci) {
        const float* wp = w + ((((ci * 8 + o) * 4 + mx) * 4 + kw) * 2);
        wr[ci] = wp[0]; wi[ci] = wp[1];
    }
    float accx = 0.f, accy = 0.f;
#pragma unroll
    for (int k = 0; k < 4; ++k) {
        int y = lane + 64 * k;
        float sx = 0.f, sy = 0.f;
#pragma unroll
        for (int ci = 0; ci < 8; ++ci) {
            float2 p = partial2[((b * 4 + kw) * 8 + ci) * 256 + y];
            sx += p.x * wr[ci] - p.y * wi[ci];
            sy += p.x * wi[ci] + p.y * wr[ci];
        }
        float ang = (PI2 / 256.0f) * m * (float)y;
        float s, c;
        sincosf(ang, &s, &c);
        accx += sx * c + sy * s;
        accy += sy * c - sx * s;
    }
    float A = foldred(accx, accy, 1, lane);
    A += __shfl_xor(A, 2, 64);
    A += __shfl_xor(A, 4, 64);
    A += __shfl_xor(A, 8, 64);
    A += __shfl_xor(A, 16, 64);
    A += __shfl_xor(A, 32, 64);
    if (lane < 2)
        c2f[(((b * 8 + o) * 8 + midx) * 4 + kw) * 2 + lane] = A;
}

// ---- Phase 3 body: h + eval for task=(bo, z); rows z and z+256 via parity.
__device__ __forceinline__ void eval2_task(const float2* __restrict__ c2,
                                           float* __restrict__ out, int task, int lane,
                                           float c1b, float s1b) {
    int z  = task & 255;
    int bo = task >> 8;

    int ll = lane & 31;
    int kw = ll & 3, midx = (ll >> 2) & 7;
    float m = (midx < 4) ? (float)midx : (float)(midx - 8);
    float2 cc = c2[(bo * 8 + midx) * 4 + kw];
    float ang = (PI2 / 512.0f) * m * (float)z;
    float s, c;
    sincosf(ang, &s, &c);
    float hx = cc.x * c - cc.y * s;
    float hy = cc.x * s + cc.y * c;
    float sg = (midx & 1) ? -1.f : 1.f;
    float gx = sg * hx, gy = sg * hy;

    float F = foldred(hx, hy, 4, lane);
    F += __shfl_xor(F, 8, 64);
    F += __shfl_xor(F, 16, 64);
    float G = foldred(gx, gy, 4, lane);
    G += __shfl_xor(G, 8, 64);
    G += __shfl_xor(G, 16, 64);
    float h0x = __shfl(F, 0, 64);
    float h1x = __shfl(F, 1, 64), h2x = __shfl(F, 2, 64), h3x = __shfl(F, 3, 64);
    float h1y = __shfl(F, 5, 64), h2y = __shfl(F, 6, 64), h3y = __shfl(F, 7, 64);
    float g0x = __shfl(G, 0, 64);
    float g1x = __shfl(G, 1, 64), g2x = __shfl(G, 2, 64), g3x = __shfl(G, 3, 64);
    float g1y = __shfl(G, 5, 64), g2y = __shfl(G, 6, 64), g3y = __shfl(G, 7, 64);

    float* orow0 = out + (size_t)(bo * 512 + z) * 512;
    float* orow1 = orow0 + 256 * 512;
    const float inv = 1.0f / 65536.0f;

    float c1 = c1b, s1 = s1b;
    const float cr = 0.99992470183839f;     // cos(2pi/512)
    const float sr = 0.012271538285720f;    // sin(2pi/512)

    float4 r0, r1, q0, q1;
    float* rp0 = &r0.x; float* rp1 = &r1.x;
    float* qp0 = &q0.x; float* qp1 = &q1.x;
#pragma unroll
    for (int j = 0; j < 4; ++j) {
        float c2a = c1 * c1 - s1 * s1, s2a = 2.f * c1 * s1;
        float c3a = c2a * c1 - s2a * s1, s3a = s2a * c1 + c2a * s1;
        float t1 = h1x * c1  - h1y * s1;
        float t2 = h2x * c2a - h2y * s2a;
        float t3 = h3x * c3a - h3y * s3a;
        rp0[j] = (h0x + t1 + t2 + t3) * inv;
        rp1[j] = (h0x - t1 + t2 - t3) * inv;
        float u1 = g1x * c1  - g1y * s1;
        float u2 = g2x * c2a - g2y * s2a;
        float u3 = g3x * c3a - g3y * s3a;
        qp0[j] = (g0x + u1 + u2 + u3) * inv;
        qp1[j] = (g0x - u1 + u2 - u3) * inv;
        float nc = c1 * cr - s1 * sr;
        float ns = s1 * cr + c1 * sr;
        c1 = nc; s1 = ns;
    }
    *(float4*)(orow0 + lane * 4)       = r0;
    *(float4*)(orow0 + 256 + lane * 4) = r1;
    *(float4*)(orow1 + lane * 4)       = q0;
    *(float4*)(orow1 + 256 + lane * 4) = q1;
}

// ---- Fused persistent cooperative kernel ----
__global__ __launch_bounds__(256, 4) void k_fused(const float* __restrict__ x,
                                                  const float* __restrict__ w1,
                                                  const float* __restrict__ w2,
                                                  float* __restrict__ pf,
                                                  float* __restrict__ c2f,
                                                  float* __restrict__ out) {
    cg::grid_group grid = cg::this_grid();
    int lane   = threadIdx.x & 63;
    int gwave  = blockIdx.x * 4 + (threadIdx.x >> 6);
    int stride = gridDim.x * 4;

    float bs, bc_;
    sincosf((PI2 / 256.0f) * (float)lane, &bs, &bc_);
    for (int t = gwave; t < 16384; t += stride)
        dft_t_row(x, pf, t, lane, bs, bc_);

    grid.sync();

    for (int t = gwave; t < 2048; t += stride)
        mix_y_task((const float2*)pf, w1, w2, c2f, t, lane);

    grid.sync();

    float s1b, c1b;
    sincosf((PI2 / 512.0f) * (float)(lane * 4), &s1b, &c1b);
    for (int t = gwave; t < 16384; t += stride)
        eval2_task((const float2*)c2f, out, t, lane, c1b, s1b);
}

// ---- Fallback standalone kernels (same bodies) ----
__global__ void k_dft_t(const float* __restrict__ x, float* __restrict__ pf) {
    int gid = blockIdx.x * blockDim.x + threadIdx.x;
    int lane = gid & 63;
    float bs, bc_;
    sincosf((PI2 / 256.0f) * (float)lane, &bs, &bc_);
    dft_t_row(x, pf, gid >> 6, lane, bs, bc_);
}
__global__ void k_mix_y(const float2* __restrict__ partial2, const float* __restrict__ w1,
                        const float* __restrict__ w2, float* __restrict__ c2f) {
    int gid = blockIdx.x * blockDim.x + threadIdx.x;
    mix_y_task(partial2, w1, w2, c2f, gid >> 6, gid & 63);
}
__global__ void k_eval2(const float2* __restrict__ c2, float* __restrict__ out) {
    int gid = blockIdx.x * blockDim.x + threadIdx.x;
    int lane = gid & 63;
    float s1b, c1b;
    sincosf((PI2 / 512.0f) * (float)(lane * 4), &s1b, &c1b);
    eval2_task(c2, out, gid >> 6, lane, c1b, s1b);
}

extern "C" void kernel_launch(void* const* d_in, const int* in_sizes, int n_in,
                              void* d_out, int out_size, void* d_ws, size_t ws_size,
                              hipStream_t stream) {
    const float* x  = (const float*)d_in[0];
    const float* w1 = (const float*)d_in[3];
    const float* w2 = (const float*)d_in[4];
    float* out = (float*)d_out;

    float* pf  = (float*)d_ws;              // [8][4][8][256] float2 = 512 KB
    float* c2f = pf + 131072;               // [8][8][8][4]   float2 = 16 KB

    int maxb = 0;
    if (hipOccupancyMaxActiveBlocksPerMultiprocessor(&maxb, (const void*)k_fused, 256, 0)
            != hipSuccess || maxb < 1)
        maxb = 2;
    int grid = maxb * 256;
    if (grid > 2048) grid = 2048;

    void* args[] = { (void*)&x, (void*)&w1, (void*)&w2,
                     (void*)&pf, (void*)&c2f, (void*)&out };
    hipError_t err = hipLaunchCooperativeKernel((const void*)k_fused, dim3(grid), dim3(256),
                                                args, 0, stream);
    if (err != hipSuccess) {
        // fallback: proven 3-kernel path
        k_dft_t<<<4096, 256, 0, stream>>>(x, pf);
        k_mix_y<<<512, 256, 0, stream>>>((const float2*)pf, w1, w2, c2f);
        k_eval2<<<4096, 256, 0, stream>>>((const float2*)c2f, out);
    }
}

// Round 6
// 41.064 us; speedup vs baseline: 3.0951x; 3.0951x over previous
//
#include <hip/hip_runtime.h>
#include <hip/hip_bf16.h>

// Problem: B=8, CIN=8, COUT=8, NX=NT=512, M1=M2=4.
// out[b,o,z,i] = Re( sum_{m,kw} c2[b,o,m,kw] e^{2pi i (m z + kw i)/512} ) / 65536
// partial layout: [b][kw][ci][y] float2 (512 KB workspace)
// K_A: t-DFT per (b,ci,y) row. K_B: per-(b,o) block computes its 32 c2 coeffs
// redundantly (8 blocks/bo), then evaluates 64 output rows.

#define PI2 6.283185307179586f

// fold-reduce: lanes with (lane&msk)==0 end holding u+partner_u; lanes with
// (lane&msk)!=0 end holding v+partner_v.
__device__ __forceinline__ float foldred(float u, float v, int msk, int lane) {
    float send = (lane & msk) ? u : v;
    float recv = __shfl_xor(send, msk, 64);
    return ((lane & msk) ? v : u) + recv;
}

// ---- K_A: t-DFT (4 modes kw=0..3) per (b,cin,y) row. One wave per row. ----
__global__ void k_dft_t(const float* __restrict__ x, float* __restrict__ pf) {
    int gid  = blockIdx.x * blockDim.x + threadIdx.x;
    int wid  = gid >> 6;          // [0, 16384)
    int lane = gid & 63;
    int bc = wid >> 8;            // b*8+cin
    int y  = wid & 255;
    const float2* row2 = (const float2*)(x + ((size_t)bc * 512 + (size_t)(2 * y)) * 512);

    float v[4];
#pragma unroll
    for (int k = 0; k < 4; ++k) v[k] = row2[lane + 64 * k].x;   // x[..,2t], t=lane+64k

    float s, c;
    sincosf((PI2 / 256.0f) * (float)lane, &s, &c);
    float pr[4], pim[4];
    pr[0] = 1.f;                         pim[0] = 0.f;
    pr[1] = c;                           pim[1] = -s;
    pr[2] = pr[1]*pr[1] - pim[1]*pim[1]; pim[2] = 2.f*pr[1]*pim[1];
    pr[3] = pr[2]*pr[1] - pim[2]*pim[1]; pim[3] = pr[2]*pim[1] + pim[2]*pr[1];

    float ar[4] = {0.f,0.f,0.f,0.f};
    float ai[4] = {0.f,0.f,0.f,0.f};
#pragma unroll
    for (int k = 0; k < 4; ++k) {
#pragma unroll
        for (int kw = 0; kw < 4; ++kw) {
            int n = (k * kw) & 3;          // twiddle = p[kw] * (-i)^n  (n compile-time)
            float rr, ri;
            if      (n == 0) { rr =  pr[kw];  ri =  pim[kw]; }
            else if (n == 1) { rr =  pim[kw]; ri = -pr[kw];  }
            else if (n == 2) { rr = -pr[kw];  ri = -pim[kw]; }
            else             { rr = -pim[kw]; ri =  pr[kw];  }
            ar[kw] += v[k] * rr;
            ai[kw] += v[k] * ri;
        }
    }
    float A0 = foldred(ar[0], ai[0], 1, lane);
    float A1 = foldred(ar[1], ai[1], 1, lane);
    float A2 = foldred(ar[2], ai[2], 1, lane);
    float A3 = foldred(ar[3], ai[3], 1, lane);
    float B0 = foldred(A0, A1, 2, lane);
    float B1 = foldred(A2, A3, 2, lane);
    float C  = foldred(B0, B1, 4, lane);
    C += __shfl_xor(C, 8, 64);
    C += __shfl_xor(C, 16, 64);
    C += __shfl_xor(C, 32, 64);
    if (lane < 8) {
        int kw = lane >> 1, ri = lane & 1;
        int b = bc >> 3, ci = bc & 7;
        pf[(((size_t)(b * 4 + kw) * 8 + ci) * 256 + y) * 2 + ri] = C;
    }
}

// ---- K_B: block = (b,o, zchunk). Phase 1: compute c2[b,o,:,:] into LDS.
//      Phase 2: eval 32 z-tasks (rows z and z+256 each). 512 blocks x 256. ----
__global__ __launch_bounds__(256) void k_mix_eval(const float2* __restrict__ partial2,
                                                  const float* __restrict__ w1,
                                                  const float* __restrict__ w2,
                                                  float* __restrict__ out) {
    __shared__ float lcf[64];     // c2[b,o][midx][kw] as re,im pairs

    int lane  = threadIdx.x & 63;
    int w     = threadIdx.x >> 6;           // wave 0..3
    int bo    = blockIdx.x >> 3;            // b*8+o
    int chunk = blockIdx.x & 7;
    int b = bo >> 3, o = bo & 7;

    // ---- Phase 1: 8 coefficient tasks per wave ----
    // base bl = e^{-2pi i lane/256}; powers bl^0..bl^4
    {
        float sb, cb;
        sincosf((PI2 / 256.0f) * (float)lane, &sb, &cb);
        float blr[5], bli[5];
        blr[0] = 1.f; bli[0] = 0.f;
        blr[1] = cb;  bli[1] = -sb;
#pragma unroll
        for (int q = 2; q <= 4; ++q) {
            blr[q] = blr[q-1]*blr[1] - bli[q-1]*bli[1];
            bli[q] = blr[q-1]*bli[1] + bli[q-1]*blr[1];
        }

#pragma unroll
        for (int j = 0; j < 8; ++j) {
            int idx  = w * 8 + j;           // [0,32)
            int midx = idx >> 2, kw = idx & 3;
            int m  = (midx < 4) ? midx : midx - 8;
            int am = (m < 0) ? -m : m;
            float px = blr[am];
            float py = (m < 0) ? -bli[am] : bli[am];   // conj for negative m
            const float* wt = (midx < 4) ? w1 : w2;
            int mx = midx & 3;

            float wr[8], wi[8];
#pragma unroll
            for (int ci = 0; ci < 8; ++ci) {
                const float* wp = wt + ((((ci * 8 + o) * 4 + mx) * 4 + kw) * 2);
                wr[ci] = wp[0]; wi[ci] = wp[1];
            }

            float accx = 0.f, accy = 0.f;
#pragma unroll
            for (int k = 0; k < 4; ++k) {
                int y = lane + 64 * k;
                float sx = 0.f, sy = 0.f;
#pragma unroll
                for (int ci = 0; ci < 8; ++ci) {
                    float2 p = partial2[((b * 4 + kw) * 8 + ci) * 256 + y];
                    sx += p.x * wr[ci] - p.y * wi[ci];
                    sy += p.x * wi[ci] + p.y * wr[ci];
                }
                // twiddle = bl^m * (-i)^{(m*k)&3}  = e^{-2pi i m y/256}
                int n = (m * k) & 3;        // two's-complement & gives mod-4 in [0,3]
                float tx = px, ty = py;
                if (n & 1) { float t = tx; tx = ty; ty = -t; }
                if (n & 2) { tx = -tx; ty = -ty; }
                accx += sx * tx - sy * ty;
                accy += sx * ty + sy * tx;
            }
            float A = foldred(accx, accy, 1, lane);   // even lanes: re, odd: im
            A += __shfl_xor(A, 2, 64);
            A += __shfl_xor(A, 4, 64);
            A += __shfl_xor(A, 8, 64);
            A += __shfl_xor(A, 16, 64);
            A += __shfl_xor(A, 32, 64);
            if (lane < 2) lcf[idx * 2 + lane] = A;
        }
    }
    __syncthreads();

    // ---- Phase 2: eval. 8 z-tasks per wave; task covers rows z and z+256. ----
    float c1b, s1b;
    sincosf((PI2 / 512.0f) * (float)(lane * 4), &s1b, &c1b);
    const float cr = 0.99992470183839f;     // cos(2pi/512)
    const float sr = 0.012271538285720f;    // sin(2pi/512)
    const float inv = 1.0f / 65536.0f;

    int ll = lane & 31;
    int kw = ll & 3, midx = (ll >> 2) & 7;
    float m = (midx < 4) ? (float)midx : (float)(midx - 8);
    float2 cc = make_float2(lcf[ll * 2], lcf[ll * 2 + 1]);
    float sgm = (midx & 1) ? -1.f : 1.f;

#pragma unroll
    for (int e = 0; e < 8; ++e) {
        int z = chunk * 32 + w * 8 + e;     // [0,256)

        float ang = (PI2 / 512.0f) * m * (float)z;
        float s, c;
        sincosf(ang, &s, &c);
        float hx = cc.x * c - cc.y * s;
        float hy = cc.x * s + cc.y * c;
        float gx = sgm * hx, gy = sgm * hy;

        float F = foldred(hx, hy, 4, lane);
        F += __shfl_xor(F, 8, 64);
        F += __shfl_xor(F, 16, 64);
        float G = foldred(gx, gy, 4, lane);
        G += __shfl_xor(G, 8, 64);
        G += __shfl_xor(G, 16, 64);
        float h0x = __shfl(F, 0, 64);
        float h1x = __shfl(F, 1, 64), h2x = __shfl(F, 2, 64), h3x = __shfl(F, 3, 64);
        float h1y = __shfl(F, 5, 64), h2y = __shfl(F, 6, 64), h3y = __shfl(F, 7, 64);
        float g0x = __shfl(G, 0, 64);
        float g1x = __shfl(G, 1, 64), g2x = __shfl(G, 2, 64), g3x = __shfl(G, 3, 64);
        float g1y = __shfl(G, 5, 64), g2y = __shfl(G, 6, 64), g3y = __shfl(G, 7, 64);

        float* orow0 = out + (size_t)(bo * 512 + z) * 512;
        float* orow1 = orow0 + 256 * 512;

        float c1 = c1b, s1 = s1b;
        float4 r0, r1, q0, q1;
        float* rp0 = &r0.x; float* rp1 = &r1.x;
        float* qp0 = &q0.x; float* qp1 = &q1.x;
#pragma unroll
        for (int j = 0; j < 4; ++j) {
            float c2a = c1 * c1 - s1 * s1, s2a = 2.f * c1 * s1;
            float c3a = c2a * c1 - s2a * s1, s3a = s2a * c1 + c2a * s1;
            float t1 = h1x * c1  - h1y * s1;
            float t2 = h2x * c2a - h2y * s2a;
            float t3 = h3x * c3a - h3y * s3a;
            rp0[j] = (h0x + t1 + t2 + t3) * inv;
            rp1[j] = (h0x - t1 + t2 - t3) * inv;
            float u1 = g1x * c1  - g1y * s1;
            float u2 = g2x * c2a - g2y * s2a;
            float u3 = g3x * c3a - g3y * s3a;
            qp0[j] = (g0x + u1 + u2 + u3) * inv;
            qp1[j] = (g0x - u1 + u2 - u3) * inv;
            float nc = c1 * cr - s1 * sr;
            float ns = s1 * cr + c1 * sr;
            c1 = nc; s1 = ns;
        }
        *(float4*)(orow0 + lane * 4)       = r0;
        *(float4*)(orow0 + 256 + lane * 4) = r1;
        *(float4*)(orow1 + lane * 4)       = q0;
        *(float4*)(orow1 + 256 + lane * 4) = q1;
    }
}

extern "C" void kernel_launch(void* const* d_in, const int* in_sizes, int n_in,
                              void* d_out, int out_size, void* d_ws, size_t ws_size,
                              hipStream_t stream) {
    const float* x  = (const float*)d_in[0];
    const float* w1 = (const float*)d_in[3];
    const float* w2 = (const float*)d_in[4];
    float* out = (float*)d_out;

    float* pf = (float*)d_ws;               // [8][4][8][256] float2 = 512 KB

    k_dft_t<<<4096, 256, 0, stream>>>(x, pf);
    k_mix_eval<<<512, 256, 0, stream>>>((const float2*)pf, w1, w2, out);
}

// Round 7
// 30.955 us; speedup vs baseline: 4.1058x; 1.3266x over previous
//
#include <hip/hip_runtime.h>
#include <hip/hip_bf16.h>

// Problem: B=8, CIN=8, COUT=8, NX=NT=512, M1=M2=4.
// out[b,o,z,i] = Re( sum_{m,kw} c2[b,o,m,kw] e^{2pi i (m z + kw i)/512} ) / 65536
// K_A: per (b,ci,y) row: t-DFT (4 modes) + y-twiddle e^{-2pi i m y/256}, block-sums
//      4 consecutive y into Yg[b][g][ci][midx*8+kw*2+ri]  (g = y>>2; 1 MB total).
// K_B: per (b,o,zchunk) block: c2 = sum_{g,ci} w (.) Yg  (cheap, coalesced),
//      then evaluates 32 z-tasks (rows z and z+256).

#define PI2 6.283185307179586f

// fold-reduce: lanes with (lane&msk)==0 end holding u+partner_u; lanes with
// (lane&msk)!=0 end holding v+partner_v.
__device__ __forceinline__ float foldred(float u, float v, int msk, int lane) {
    float send = (lane & msk) ? u : v;
    float recv = __shfl_xor(send, msk, 64);
    return ((lane & msk) ? v : u) + recv;
}

// ---- K_A: t-DFT + y-twiddle + 4-row block sum. One wave per row, 4096 blocks. ----
__global__ void k_dft_t(const float* __restrict__ x, float* __restrict__ Yg) {
    __shared__ float vals[4][64];
    int lane = threadIdx.x & 63;
    int w    = threadIdx.x >> 6;
    int wid  = blockIdx.x * 4 + w;       // [0, 16384)
    int bc = wid >> 8;                   // b*8+ci  (constant within block)
    int y  = wid & 255;
    const float2* row2 = (const float2*)(x + ((size_t)bc * 512 + (size_t)(2 * y)) * 512);

    float v[4];
#pragma unroll
    for (int k = 0; k < 4; ++k) v[k] = row2[lane + 64 * k].x;   // x[..,2t], t=lane+64k

    float s, c;
    sincosf((PI2 / 256.0f) * (float)lane, &s, &c);
    float pr[4], pim[4];
    pr[0] = 1.f;                         pim[0] = 0.f;
    pr[1] = c;                           pim[1] = -s;
    pr[2] = pr[1]*pr[1] - pim[1]*pim[1]; pim[2] = 2.f*pr[1]*pim[1];
    pr[3] = pr[2]*pr[1] - pim[2]*pim[1]; pim[3] = pr[2]*pim[1] + pim[2]*pr[1];

    float ar[4] = {0.f,0.f,0.f,0.f};
    float ai[4] = {0.f,0.f,0.f,0.f};
#pragma unroll
    for (int k = 0; k < 4; ++k) {
#pragma unroll
        for (int kw = 0; kw < 4; ++kw) {
            int n = (k * kw) & 3;          // twiddle = p[kw] * (-i)^n  (n compile-time)
            float rr, ri;
            if      (n == 0) { rr =  pr[kw];  ri =  pim[kw]; }
            else if (n == 1) { rr =  pim[kw]; ri = -pr[kw];  }
            else if (n == 2) { rr = -pr[kw];  ri = -pim[kw]; }
            else             { rr = -pim[kw]; ri =  pr[kw];  }
            ar[kw] += v[k] * rr;
            ai[kw] += v[k] * ri;
        }
    }
    // fold: afterwards EVERY lane l holds component (kw=(l>>1)&3, ri=l&1)
    float A0 = foldred(ar[0], ai[0], 1, lane);
    float A1 = foldred(ar[1], ai[1], 1, lane);
    float A2 = foldred(ar[2], ai[2], 1, lane);
    float A3 = foldred(ar[3], ai[3], 1, lane);
    float B0 = foldred(A0, A1, 2, lane);
    float B1 = foldred(A2, A3, 2, lane);
    float C  = foldred(B0, B1, 4, lane);
    C += __shfl_xor(C, 8, 64);
    C += __shfl_xor(C, 16, 64);
    C += __shfl_xor(C, 32, 64);

    // y-twiddle: lane role (midx=lane>>3, kw, ri); multiply p by e^{-2pi i m y/256}
    float partner = __shfl_xor(C, 1, 64);
    int midx = lane >> 3;
    float mf = (midx < 4) ? (float)midx : (float)(midx - 8);
    float sn, cs;
    sincosf((PI2 / 256.0f) * mf * (float)y, &sn, &cs);
    float ty  = -sn;                       // twiddle = cs + i*ty
    float sel = (lane & 1) ? ty : -ty;     // re-lane: -ty*pim ; im-lane: +ty*pre
    vals[w][lane] = C * cs + partner * sel;
    __syncthreads();

    if (threadIdx.x < 64) {
        int b = bc >> 3, ci = bc & 7, g = blockIdx.x & 63;
        float sum = vals[0][lane] + vals[1][lane] + vals[2][lane] + vals[3][lane];
        Yg[((size_t)((b * 64 + g) * 8 + ci)) * 64 + lane] = sum;
    }
}

// ---- K_B: block = (b,o,zchunk). Phase 1: c2 from Yg (coalesced). Phase 2: eval. ----
__global__ __launch_bounds__(256) void k_mix_eval(const float* __restrict__ Yg,
                                                  const float* __restrict__ w1,
                                                  const float* __restrict__ w2,
                                                  float* __restrict__ out) {
    __shared__ float vals[4][64];
    __shared__ float lcf[64];     // c2[(midx*4+kw)*2+ri]

    int lane  = threadIdx.x & 63;
    int w     = threadIdx.x >> 6;           // wave 0..3
    int bo    = blockIdx.x >> 3;            // b*8+o
    int chunk = blockIdx.x & 7;
    int b = bo >> 3, o = bo & 7;

    // ---- Phase 1: lane role (midx,kw,ri) = lane bits; sum over g (strided by wave) and ci
    {
        int midx = lane >> 3, kw = (lane >> 1) & 3, ri = lane & 1, mx = midx & 3;
        const float* wt = (midx < 4) ? w1 : w2;
        float wr_[8], swi_[8];
#pragma unroll
        for (int ci = 0; ci < 8; ++ci) {
            const float* wp = wt + ((((ci * 8 + o) * 4 + mx) * 4 + kw) * 2);
            wr_[ci]  = wp[0];
            swi_[ci] = ri ? wp[1] : -wp[1];
        }
        float acc = 0.f;
        for (int g = w; g < 64; g += 4) {
            const float* Yp = Yg + ((size_t)((b * 64 + g) * 8)) * 64 + lane;
#pragma unroll
            for (int ci = 0; ci < 8; ++ci) {
                float Yv = Yp[ci * 64];
                float pt = __shfl_xor(Yv, 1, 64);
                acc += Yv * wr_[ci] + pt * swi_[ci];
            }
        }
        vals[w][lane] = acc;
    }
    __syncthreads();
    if (w == 0)
        lcf[lane] = vals[0][lane] + vals[1][lane] + vals[2][lane] + vals[3][lane];
    __syncthreads();

    // ---- Phase 2: eval. 8 z-tasks per wave; task covers rows z and z+256. ----
    float c1b, s1b;
    sincosf((PI2 / 512.0f) * (float)(lane * 4), &s1b, &c1b);
    const float cr = 0.99992470183839f;     // cos(2pi/512)
    const float sr = 0.012271538285720f;    // sin(2pi/512)
    const float inv = 1.0f / 65536.0f;

    int ll = lane & 31;
    int kw = ll & 3, midx = (ll >> 2) & 7;
    float m = (midx < 4) ? (float)midx : (float)(midx - 8);
    float2 cc = make_float2(lcf[ll * 2], lcf[ll * 2 + 1]);
    float sgm = (midx & 1) ? -1.f : 1.f;

#pragma unroll
    for (int e = 0; e < 8; ++e) {
        int z = chunk * 32 + w * 8 + e;     // [0,256)

        float ang = (PI2 / 512.0f) * m * (float)z;
        float s, c;
        sincosf(ang, &s, &c);
        float hx = cc.x * c - cc.y * s;
        float hy = cc.x * s + cc.y * c;
        float gx = sgm * hx, gy = sgm * hy;

        float F = foldred(hx, hy, 4, lane);
        F += __shfl_xor(F, 8, 64);
        F += __shfl_xor(F, 16, 64);
        float G = foldred(gx, gy, 4, lane);
        G += __shfl_xor(G, 8, 64);
        G += __shfl_xor(G, 16, 64);
        float h0x = __shfl(F, 0, 64);
        float h1x = __shfl(F, 1, 64), h2x = __shfl(F, 2, 64), h3x = __shfl(F, 3, 64);
        float h1y = __shfl(F, 5, 64), h2y = __shfl(F, 6, 64), h3y = __shfl(F, 7, 64);
        float g0x = __shfl(G, 0, 64);
        float g1x = __shfl(G, 1, 64), g2x = __shfl(G, 2, 64), g3x = __shfl(G, 3, 64);
        float g1y = __shfl(G, 5, 64), g2y = __shfl(G, 6, 64), g3y = __shfl(G, 7, 64);

        float* orow0 = out + (size_t)(bo * 512 + z) * 512;
        float* orow1 = orow0 + 256 * 512;

        float c1 = c1b, s1 = s1b;
        float4 r0, r1, q0, q1;
        float* rp0 = &r0.x; float* rp1 = &r1.x;
        float* qp0 = &q0.x; float* qp1 = &q1.x;
#pragma unroll
        for (int j = 0; j < 4; ++j) {
            float c2a = c1 * c1 - s1 * s1, s2a = 2.f * c1 * s1;
            float c3a = c2a * c1 - s2a * s1, s3a = s2a * c1 + c2a * s1;
            float t1 = h1x * c1  - h1y * s1;
            float t2 = h2x * c2a - h2y * s2a;
            float t3 = h3x * c3a - h3y * s3a;
            rp0[j] = (h0x + t1 + t2 + t3) * inv;
            rp1[j] = (h0x - t1 + t2 - t3) * inv;
            float u1 = g1x * c1  - g1y * s1;
            float u2 = g2x * c2a - g2y * s2a;
            float u3 = g3x * c3a - g3y * s3a;
            qp0[j] = (g0x + u1 + u2 + u3) * inv;
            qp1[j] = (g0x - u1 + u2 - u3) * inv;
            float nc = c1 * cr - s1 * sr;
            float ns = s1 * cr + c1 * sr;
            c1 = nc; s1 = ns;
        }
        *(float4*)(orow0 + lane * 4)       = r0;
        *(float4*)(orow0 + 256 + lane * 4) = r1;
        *(float4*)(orow1 + lane * 4)       = q0;
        *(float4*)(orow1 + 256 + lane * 4) = q1;
    }
}

extern "C" void kernel_launch(void* const* d_in, const int* in_sizes, int n_in,
                              void* d_out, int out_size, void* d_ws, size_t ws_size,
                              hipStream_t stream) {
    const float* x  = (const float*)d_in[0];
    const float* w1 = (const float*)d_in[3];
    const float* w2 = (const float*)d_in[4];
    float* out = (float*)d_out;

    float* Yg = (float*)d_ws;               // [8][64][8][64] floats = 1 MB

    k_dft_t<<<4096, 256, 0, stream>>>(x, Yg);
    k_mix_eval<<<512, 256, 0, stream>>>(Yg, w1, w2, out);
}

// Round 8
// 28.742 us; speedup vs baseline: 4.4219x; 1.0770x over previous
//
#include <hip/hip_runtime.h>
#include <hip/hip_bf16.h>

// Problem: B=8, CIN=8, COUT=8, NX=NT=512, M1=M2=4.
// out[b,o,z,i] = Re( sum_{m,kw} c2[b,o,m,kw] e^{2pi i (m z + kw i)/512} ) / 65536
// K_A: per (b,ci,y) row: t-DFT (4 modes) + y-twiddle e^{-2pi i m y/256}; 512-thread
//      block sums its 8 rows -> Yg[b][g][ci][64], g = y>>3 (32 groups, 512 KB).
// K_B: 2048 blocks = (bo, chunk<32). Phase 1: c2 = sum_{g,ci} w (.) Yg (64 coalesced
//      loads/wave). Phase 2: eval 8 z-rows (each covering z and z+256) at 32 waves/CU.

#define PI2 6.283185307179586f

// fold-reduce: lanes with (lane&msk)==0 end holding u+partner_u; lanes with
// (lane&msk)!=0 end holding v+partner_v.
__device__ __forceinline__ float foldred(float u, float v, int msk, int lane) {
    float send = (lane & msk) ? u : v;
    float recv = __shfl_xor(send, msk, 64);
    return ((lane & msk) ? v : u) + recv;
}

// ---- K_A: t-DFT + y-twiddle + 8-row block sum. One wave per row, 2048x512. ----
__global__ __launch_bounds__(512) void k_dft_t(const float* __restrict__ x,
                                               float* __restrict__ Yg) {
    __shared__ float vals[8][64];
    int lane = threadIdx.x & 63;
    int w    = threadIdx.x >> 6;         // 0..7
    int wid  = blockIdx.x * 8 + w;       // [0, 16384)
    int bc = wid >> 8;                   // b*8+ci (constant within block)
    int y  = wid & 255;
    const float2* row2 = (const float2*)(x + ((size_t)bc * 512 + (size_t)(2 * y)) * 512);

    float v[4];
#pragma unroll
    for (int k = 0; k < 4; ++k) v[k] = row2[lane + 64 * k].x;   // x[..,2t], t=lane+64k

    float s, c;
    sincosf((PI2 / 256.0f) * (float)lane, &s, &c);
    float pr[4], pim[4];
    pr[0] = 1.f;                         pim[0] = 0.f;
    pr[1] = c;                           pim[1] = -s;
    pr[2] = pr[1]*pr[1] - pim[1]*pim[1]; pim[2] = 2.f*pr[1]*pim[1];
    pr[3] = pr[2]*pr[1] - pim[2]*pim[1]; pim[3] = pr[2]*pim[1] + pim[2]*pr[1];

    float ar[4] = {0.f,0.f,0.f,0.f};
    float ai[4] = {0.f,0.f,0.f,0.f};
#pragma unroll
    for (int k = 0; k < 4; ++k) {
#pragma unroll
        for (int kw = 0; kw < 4; ++kw) {
            int n = (k * kw) & 3;          // twiddle = p[kw] * (-i)^n  (n compile-time)
            float rr, ri;
            if      (n == 0) { rr =  pr[kw];  ri =  pim[kw]; }
            else if (n == 1) { rr =  pim[kw]; ri = -pr[kw];  }
            else if (n == 2) { rr = -pr[kw];  ri = -pim[kw]; }
            else             { rr = -pim[kw]; ri =  pr[kw];  }
            ar[kw] += v[k] * rr;
            ai[kw] += v[k] * ri;
        }
    }
    // fold: afterwards EVERY lane l holds component (kw=(l>>1)&3, ri=l&1)
    float A0 = foldred(ar[0], ai[0], 1, lane);
    float A1 = foldred(ar[1], ai[1], 1, lane);
    float A2 = foldred(ar[2], ai[2], 1, lane);
    float A3 = foldred(ar[3], ai[3], 1, lane);
    float B0 = foldred(A0, A1, 2, lane);
    float B1 = foldred(A2, A3, 2, lane);
    float C  = foldred(B0, B1, 4, lane);
    C += __shfl_xor(C, 8, 64);
    C += __shfl_xor(C, 16, 64);
    C += __shfl_xor(C, 32, 64);

    // y-twiddle: lane role (midx=lane>>3, kw, ri); multiply by e^{-2pi i m y/256}
    float partner = __shfl_xor(C, 1, 64);
    int midx = lane >> 3;
    float mf = (midx < 4) ? (float)midx : (float)(midx - 8);
    float sn, cs;
    sincosf((PI2 / 256.0f) * mf * (float)y, &sn, &cs);
    float ty  = -sn;                       // twiddle = cs + i*ty
    float sel = (lane & 1) ? ty : -ty;     // re-lane: -ty*Im ; im-lane: +ty*Re
    vals[w][lane] = C * cs + partner * sel;
    __syncthreads();

    if (threadIdx.x < 64) {
        int b = bc >> 3, ci = bc & 7, g = blockIdx.x & 31;
        float sum = 0.f;
#pragma unroll
        for (int q = 0; q < 8; ++q) sum += vals[q][lane];
        Yg[((size_t)((b * 32 + g) * 8 + ci)) * 64 + lane] = sum;
    }
}

// ---- K_B: block = (bo, chunk<32). Phase 1: c2 from Yg. Phase 2: eval 8 z. ----
__global__ __launch_bounds__(256) void k_mix_eval(const float* __restrict__ Yg,
                                                  const float* __restrict__ w1,
                                                  const float* __restrict__ w2,
                                                  float* __restrict__ out) {
    __shared__ float vals[4][64];
    __shared__ float lcf[64];     // c2[midx*8+kw*2+ri] == index by lane role

    int lane  = threadIdx.x & 63;
    int w     = threadIdx.x >> 6;           // wave 0..3
    int bo    = blockIdx.x >> 5;            // b*8+o
    int chunk = blockIdx.x & 31;
    int b = bo >> 3, o = bo & 7;

    // ---- Phase 1: lane role (midx,kw,ri); sum over g (strided by wave) and ci
    {
        int midx = lane >> 3, kw = (lane >> 1) & 3, ri = lane & 1, mx = midx & 3;
        const float* wt = (midx < 4) ? w1 : w2;
        float wr_[8], swi_[8];
#pragma unroll
        for (int ci = 0; ci < 8; ++ci) {
            const float* wp = wt + ((((ci * 8 + o) * 4 + mx) * 4 + kw) * 2);
            wr_[ci]  = wp[0];
            swi_[ci] = ri ? wp[1] : -wp[1];
        }
        float acc = 0.f;
#pragma unroll
        for (int gi = 0; gi < 8; ++gi) {
            int g = w + gi * 4;
            const float* Yp = Yg + ((size_t)((b * 32 + g) * 8)) * 64 + lane;
#pragma unroll
            for (int ci = 0; ci < 8; ++ci) {
                float Yv = Yp[ci * 64];
                float pt = __shfl_xor(Yv, 1, 64);
                acc += Yv * wr_[ci] + pt * swi_[ci];
            }
        }
        vals[w][lane] = acc;
    }
    __syncthreads();
    if (w == 0)
        lcf[lane] = vals[0][lane] + vals[1][lane] + vals[2][lane] + vals[3][lane];
    __syncthreads();

    // ---- Phase 2: eval. 2 z-tasks per wave; task covers rows z and z+256. ----
    float c1b, s1b;
    sincosf((PI2 / 512.0f) * (float)(lane * 4), &s1b, &c1b);
    const float cr = 0.99992470183839f;     // cos(2pi/512)
    const float sr = 0.012271538285720f;    // sin(2pi/512)
    const float inv = 1.0f / 65536.0f;

    int ll = lane & 31;
    int kw = ll & 3, midx = (ll >> 2) & 7;
    float m = (midx < 4) ? (float)midx : (float)(midx - 8);
    float2 cc = make_float2(lcf[ll * 2], lcf[ll * 2 + 1]);
    float sgm = (midx & 1) ? -1.f : 1.f;

#pragma unroll
    for (int e = 0; e < 2; ++e) {
        int z = chunk * 8 + w * 2 + e;      // [0,256)

        float ang = (PI2 / 512.0f) * m * (float)z;
        float s, c;
        sincosf(ang, &s, &c);
        float hx = cc.x * c - cc.y * s;
        float hy = cc.x * s + cc.y * c;
        float gx = sgm * hx, gy = sgm * hy;

        float F = foldred(hx, hy, 4, lane);
        F += __shfl_xor(F, 8, 64);
        F += __shfl_xor(F, 16, 64);
        float G = foldred(gx, gy, 4, lane);
        G += __shfl_xor(G, 8, 64);
        G += __shfl_xor(G, 16, 64);
        float h0x = __shfl(F, 0, 64);
        float h1x = __shfl(F, 1, 64), h2x = __shfl(F, 2, 64), h3x = __shfl(F, 3, 64);
        float h1y = __shfl(F, 5, 64), h2y = __shfl(F, 6, 64), h3y = __shfl(F, 7, 64);
        float g0x = __shfl(G, 0, 64);
        float g1x = __shfl(G, 1, 64), g2x = __shfl(G, 2, 64), g3x = __shfl(G, 3, 64);
        float g1y = __shfl(G, 5, 64), g2y = __shfl(G, 6, 64), g3y = __shfl(G, 7, 64);

        float* orow0 = out + (size_t)(bo * 512 + z) * 512;
        float* orow1 = orow0 + 256 * 512;

        float c1 = c1b, s1 = s1b;
        float4 r0, r1, q0, q1;
        float* rp0 = &r0.x; float* rp1 = &r1.x;
        float* qp0 = &q0.x; float* qp1 = &q1.x;
#pragma unroll
        for (int j = 0; j < 4; ++j) {
            float c2a = c1 * c1 - s1 * s1, s2a = 2.f * c1 * s1;
            float c3a = c2a * c1 - s2a * s1, s3a = s2a * c1 + c2a * s1;
            float t1 = h1x * c1  - h1y * s1;
            float t2 = h2x * c2a - h2y * s2a;
            float t3 = h3x * c3a - h3y * s3a;
            rp0[j] = (h0x + t1 + t2 + t3) * inv;
            rp1[j] = (h0x - t1 + t2 - t3) * inv;
            float u1 = g1x * c1  - g1y * s1;
            float u2 = g2x * c2a - g2y * s2a;
            float u3 = g3x * c3a - g3y * s3a;
            qp0[j] = (g0x + u1 + u2 + u3) * inv;
            qp1[j] = (g0x - u1 + u2 - u3) * inv;
            float nc = c1 * cr - s1 * sr;
            float ns = s1 * cr + c1 * sr;
            c1 = nc; s1 = ns;
        }
        *(float4*)(orow0 + lane * 4)       = r0;
        *(float4*)(orow0 + 256 + lane * 4) = r1;
        *(float4*)(orow1 + lane * 4)       = q0;
        *(float4*)(orow1 + 256 + lane * 4) = q1;
    }
}

extern "C" void kernel_launch(void* const* d_in, const int* in_sizes, int n_in,
                              void* d_out, int out_size, void* d_ws, size_t ws_size,
                              hipStream_t stream) {
    const float* x  = (const float*)d_in[0];
    const float* w1 = (const float*)d_in[3];
    const float* w2 = (const float*)d_in[4];
    float* out = (float*)d_out;

    float* Yg = (float*)d_ws;               // [8][32][8][64] floats = 512 KB

    k_dft_t<<<2048, 512, 0, stream>>>(x, Yg);
    k_mix_eval<<<2048, 256, 0, stream>>>(Yg, w1, w2, out);
}

// Round 10
// 25.484 us; speedup vs baseline: 4.9873x; 1.1278x over previous
//
#include <hip/hip_runtime.h>
#include <hip/hip_bf16.h>

// Problem: B=8, CIN=8, COUT=8, NX=NT=512, M1=M2=4.
// out[b,o,z,i] = Re( sum_{m,kw} c2[b,o,m,kw] e^{2pi i (m z + kw i)/512} ) / 65536
// K_A: per (b,ci) pair-of-rows wave: t-DFT (4 modes, float4 loads, half-period
//      sign trick) + y-twiddle; 512-thread block sums 16 rows -> Yg[b][g][ci][64],
//      g = y>>4 (16 groups, 256 KB).
// K_B: 2048 blocks = (bo, chunk<32). Phase 1: c2 = sum_{g,ci} w (.) Yg.
//      Phase 2: eval 8 z-rows (each covering z and z+256), nontemporal stores.

#define PI2 6.283185307179586f

typedef float vfloat4 __attribute__((ext_vector_type(4)));   // native clang vector

// fold-reduce: lanes with (lane&msk)==0 end holding u+partner_u; lanes with
// (lane&msk)!=0 end holding v+partner_v.
__device__ __forceinline__ float foldred(float u, float v, int msk, int lane) {
    float send = (lane & msk) ? u : v;
    float recv = __shfl_xor(send, msk, 64);
    return ((lane & msk) ? v : u) + recv;
}

// full fold of 4 complex accumulators -> every lane holds (kw=(l>>1)&3, ri=l&1)
__device__ __forceinline__ float fold8(const float* ar, const float* ai, int lane) {
    float A0 = foldred(ar[0], ai[0], 1, lane);
    float A1 = foldred(ar[1], ai[1], 1, lane);
    float A2 = foldred(ar[2], ai[2], 1, lane);
    float A3 = foldred(ar[3], ai[3], 1, lane);
    float B0 = foldred(A0, A1, 2, lane);
    float B1 = foldred(A2, A3, 2, lane);
    float C  = foldred(B0, B1, 4, lane);
    C += __shfl_xor(C, 8, 64);
    C += __shfl_xor(C, 16, 64);
    C += __shfl_xor(C, 32, 64);
    return C;
}

// ---- K_A: t-DFT + y-twiddle, 2 rows per wave, 16-row block sum. 1024x512. ----
__global__ __launch_bounds__(512) void k_dft_t(const float* __restrict__ x,
                                               float* __restrict__ Yg) {
    __shared__ float vals[8][64];
    int lane = threadIdx.x & 63;
    int w    = threadIdx.x >> 6;         // 0..7
    int bc   = blockIdx.x >> 4;          // b*8+ci
    int g    = blockIdx.x & 15;
    int y0   = 2 * (g * 8 + w);          // rows y0, y0+1 (xs-rows)

    const vfloat4* r0 = (const vfloat4*)(x + ((size_t)bc * 512 + (size_t)(2 * y0)) * 512);
    const vfloat4* r1 = (const vfloat4*)(x + ((size_t)bc * 512 + (size_t)(2 * y0 + 2)) * 512);
    vfloat4 a0 = __builtin_nontemporal_load(&r0[lane]);
    vfloat4 a1 = __builtin_nontemporal_load(&r0[lane + 64]);
    vfloat4 b0 = __builtin_nontemporal_load(&r1[lane]);
    vfloat4 b1 = __builtin_nontemporal_load(&r1[lane + 64]);
    // lane covers t = {2L, 2L+1} (elems 0,2) and t+128 (second load, sign trick)

    // twE = e^{-2pi i (2L)/256}; twO = twE * e^{-2pi i/256}; powers ^kw
    float s, c;
    sincosf((PI2 / 128.0f) * (float)lane, &s, &c);
    float er[4], ei[4], orE[4], oiE[4];
    er[0] = 1.f; ei[0] = 0.f;
    er[1] = c;   ei[1] = -s;
    er[2] = er[1]*er[1] - ei[1]*ei[1];  ei[2] = 2.f*er[1]*ei[1];
    er[3] = er[2]*er[1] - ei[2]*ei[1];  ei[3] = er[2]*ei[1] + ei[2]*er[1];
    const float rr1 = 0.999698818696204f, ri1 = -0.024541228522912f; // e^{-2pi i/256}
    const float rr2 = 0.998795456205172f, ri2 = -0.049067674327418f; // ^2
    const float rr3 = 0.997290456678690f, ri3 = -0.073564563599667f; // ^3
    orE[0] = 1.f; oiE[0] = 0.f;
    orE[1] = er[1]*rr1 - ei[1]*ri1;  oiE[1] = er[1]*ri1 + ei[1]*rr1;
    orE[2] = er[2]*rr2 - ei[2]*ri2;  oiE[2] = er[2]*ri2 + ei[2]*rr2;
    orE[3] = er[3]*rr3 - ei[3]*ri3;  oiE[3] = er[3]*ri3 + ei[3]*rr3;

    float arA[4], aiA[4], arB[4], aiB[4];
#pragma unroll
    for (int kw = 0; kw < 4; ++kw) {
        float sgn = (kw & 1) ? -1.f : 1.f;      // tw(t+128)^kw = (-1)^kw tw(t)^kw
        float eA = a0[0] + sgn * a1[0], oA = a0[2] + sgn * a1[2];
        float eB = b0[0] + sgn * b1[0], oB = b0[2] + sgn * b1[2];
        arA[kw] = eA * er[kw] + oA * orE[kw];
        aiA[kw] = eA * ei[kw] + oA * oiE[kw];
        arB[kw] = eB * er[kw] + oB * orE[kw];
        aiB[kw] = eB * ei[kw] + oB * oiE[kw];
    }
    float Ca = fold8(arA, aiA, lane);
    float Cb = fold8(arB, aiB, lane);

    // y-twiddle e^{-2pi i m y/256}: row0 by sincosf, row1 by constant rotation
    int midx = lane >> 3;
    float mf = (midx < 4) ? (float)midx : (float)(midx - 8);
    float snm, csm;
    sincosf((PI2 / 256.0f) * mf * (float)y0, &snm, &csm);
    float ty0 = -snm;                          // tw(y0) = csm + i ty0
    float smm, cmm;
    sincosf((PI2 / 256.0f) * mf, &smm, &cmm);
    float cs1 = csm * cmm + ty0 * smm;         // tw(y0+1) = tw(y0)*(cmm - i smm)
    float ty1 = ty0 * cmm - csm * smm;

    float pa = __shfl_xor(Ca, 1, 64);
    float pb = __shfl_xor(Cb, 1, 64);
    float selA = (lane & 1) ? ty0 : -ty0;
    float selB = (lane & 1) ? ty1 : -ty1;
    vals[w][lane] = Ca * csm + pa * selA + Cb * cs1 + pb * selB;
    __syncthreads();

    if (threadIdx.x < 64) {
        int b = bc >> 3, ci = bc & 7;
        float sum = 0.f;
#pragma unroll
        for (int q = 0; q < 8; ++q) sum += vals[q][lane];
        Yg[((size_t)((b * 16 + g) * 8 + ci)) * 64 + lane] = sum;
    }
}

// ---- K_B: block = (bo, chunk<32). Phase 1: c2 from Yg. Phase 2: eval 8 z. ----
__global__ __launch_bounds__(256) void k_mix_eval(const float* __restrict__ Yg,
                                                  const float* __restrict__ w1,
                                                  const float* __restrict__ w2,
                                                  float* __restrict__ out) {
    __shared__ float vals[4][64];
    __shared__ float lcf[64];     // c2[midx*8+kw*2+ri], indexed by lane role

    int lane  = threadIdx.x & 63;
    int w     = threadIdx.x >> 6;           // wave 0..3
    int bo    = blockIdx.x >> 5;            // b*8+o
    int chunk = blockIdx.x & 31;
    int b = bo >> 3, o = bo & 7;

    // ---- Phase 1: lane role (midx,kw,ri); sum over g (strided by wave) and ci
    {
        int midx = lane >> 3, kw = (lane >> 1) & 3, ri = lane & 1, mx = midx & 3;
        const float* wt = (midx < 4) ? w1 : w2;
        float wr_[8], swi_[8];
#pragma unroll
        for (int ci = 0; ci < 8; ++ci) {
            const float* wp = wt + ((((ci * 8 + o) * 4 + mx) * 4 + kw) * 2);
            wr_[ci]  = wp[0];
            swi_[ci] = ri ? wp[1] : -wp[1];
        }
        float acc = 0.f;
#pragma unroll
        for (int gi = 0; gi < 4; ++gi) {
            int g = w + gi * 4;
            const float* Yp = Yg + ((size_t)((b * 16 + g) * 8)) * 64 + lane;
#pragma unroll
            for (int ci = 0; ci < 8; ++ci) {
                float Yv = Yp[ci * 64];
                float pt = __shfl_xor(Yv, 1, 64);
                acc += Yv * wr_[ci] + pt * swi_[ci];
            }
        }
        vals[w][lane] = acc;
    }
    __syncthreads();
    if (w == 0)
        lcf[lane] = vals[0][lane] + vals[1][lane] + vals[2][lane] + vals[3][lane];
    __syncthreads();

    // ---- Phase 2: eval. 2 z-tasks per wave; task covers rows z and z+256. ----
    float c1b, s1b;
    sincosf((PI2 / 512.0f) * (float)(lane * 4), &s1b, &c1b);
    const float cr = 0.99992470183839f;     // cos(2pi/512)
    const float sr = 0.012271538285720f;    // sin(2pi/512)
    const float inv = 1.0f / 65536.0f;

    int ll = lane & 31;
    int kw = ll & 3, midx = (ll >> 2) & 7;
    float m = (midx < 4) ? (float)midx : (float)(midx - 8);
    float2 cc = make_float2(lcf[ll * 2], lcf[ll * 2 + 1]);
    float sgm = (midx & 1) ? -1.f : 1.f;

#pragma unroll
    for (int e = 0; e < 2; ++e) {
        int z = chunk * 8 + w * 2 + e;      // [0,256)

        float ang = (PI2 / 512.0f) * m * (float)z;
        float s, c;
        sincosf(ang, &s, &c);
        float hx = cc.x * c - cc.y * s;
        float hy = cc.x * s + cc.y * c;
        float gx = sgm * hx, gy = sgm * hy;

        float F = foldred(hx, hy, 4, lane);
        F += __shfl_xor(F, 8, 64);
        F += __shfl_xor(F, 16, 64);
        float G = foldred(gx, gy, 4, lane);
        G += __shfl_xor(G, 8, 64);
        G += __shfl_xor(G, 16, 64);
        float h0x = __shfl(F, 0, 64);
        float h1x = __shfl(F, 1, 64), h2x = __shfl(F, 2, 64), h3x = __shfl(F, 3, 64);
        float h1y = __shfl(F, 5, 64), h2y = __shfl(F, 6, 64), h3y = __shfl(F, 7, 64);
        float g0x = __shfl(G, 0, 64);
        float g1x = __shfl(G, 1, 64), g2x = __shfl(G, 2, 64), g3x = __shfl(G, 3, 64);
        float g1y = __shfl(G, 5, 64), g2y = __shfl(G, 6, 64), g3y = __shfl(G, 7, 64);

        float* orow0 = out + (size_t)(bo * 512 + z) * 512;
        float* orow1 = orow0 + 256 * 512;

        float c1 = c1b, s1 = s1b;
        vfloat4 r0, r1, q0, q1;
#pragma unroll
        for (int j = 0; j < 4; ++j) {
            float c2a = c1 * c1 - s1 * s1, s2a = 2.f * c1 * s1;
            float c3a = c2a * c1 - s2a * s1, s3a = s2a * c1 + c2a * s1;
            float t1 = h1x * c1  - h1y * s1;
            float t2 = h2x * c2a - h2y * s2a;
            float t3 = h3x * c3a - h3y * s3a;
            r0[j] = (h0x + t1 + t2 + t3) * inv;
            r1[j] = (h0x - t1 + t2 - t3) * inv;
            float u1 = g1x * c1  - g1y * s1;
            float u2 = g2x * c2a - g2y * s2a;
            float u3 = g3x * c3a - g3y * s3a;
            q0[j] = (g0x + u1 + u2 + u3) * inv;
            q1[j] = (g0x - u1 + u2 - u3) * inv;
            float nc = c1 * cr - s1 * sr;
            float ns = s1 * cr + c1 * sr;
            c1 = nc; s1 = ns;
        }
        __builtin_nontemporal_store(r0, (vfloat4*)(orow0 + lane * 4));
        __builtin_nontemporal_store(r1, (vfloat4*)(orow0 + 256 + lane * 4));
        __builtin_nontemporal_store(q0, (vfloat4*)(orow1 + lane * 4));
        __builtin_nontemporal_store(q1, (vfloat4*)(orow1 + 256 + lane * 4));
    }
}

extern "C" void kernel_launch(void* const* d_in, const int* in_sizes, int n_in,
                              void* d_out, int out_size, void* d_ws, size_t ws_size,
                              hipStream_t stream) {
    const float* x  = (const float*)d_in[0];
    const float* w1 = (const float*)d_in[3];
    const float* w2 = (const float*)d_in[4];
    float* out = (float*)d_out;

    float* Yg = (float*)d_ws;               // [8][16][8][64] floats = 256 KB

    k_dft_t<<<1024, 512, 0, stream>>>(x, Yg);
    k_mix_eval<<<2048, 256, 0, stream>>>(Yg, w1, w2, out);
}